// Round 1
// baseline (3091.603 us; speedup 1.0000x reference)
//
#include <hip/hip_runtime.h>

#define B_ 256
#define T_ 512
#define I_ 64
#define H_ 512
#define O_ 16

typedef _Float16 half8 __attribute__((ext_vector_type(8)));
typedef float    f32x4 __attribute__((ext_vector_type(4)));

#define MFMA16(a, b, c) __builtin_amdgcn_mfma_f32_16x16x32_f16((a), (b), (c), 0, 0, 0)

__device__ inline half8 cvt_h8(f32x4 a, f32x4 b) {
  half8 v;
  v[0] = (_Float16)a[0]; v[1] = (_Float16)a[1]; v[2] = (_Float16)a[2]; v[3] = (_Float16)a[3];
  v[4] = (_Float16)b[0]; v[5] = (_Float16)b[1]; v[6] = (_Float16)b[2]; v[7] = (_Float16)b[3];
  return v;
}

// Persistent RNN: 32 blocks = 16 groups x 2 roles. Group g handles batches
// [16g, 16g+16); role r holds W_hh rows [256r, 256r+256) as resident MFMA
// B-fragments in VGPRs (256 VGPRs/thread -> __launch_bounds__(256,1)).
// h lives in LDS in A-fragment order: hfrag[(kc*64 + lane)*8 + e] = h[m][k],
// lane = m + 16*q, k = kc*32 + q*8 + e  (conflict-free ds_read_b128).
__global__ __launch_bounds__(256, 1)
void rnn_persist(const float* __restrict__ x, const float* __restrict__ h0,
                 const float* __restrict__ W_ih, const float* __restrict__ W_hh,
                 const float* __restrict__ b_ih, const float* __restrict__ b_hh,
                 const float* __restrict__ W_fc, const float* __restrict__ b_fc,
                 float* __restrict__ out, _Float16* __restrict__ Xbuf,
                 int* __restrict__ flags) {
  const int tid = threadIdx.x;
  const int L   = tid & 63;        // lane
  const int w   = tid >> 6;        // wave 0..3
  const int m15 = L & 15;
  const int q   = (L >> 4) & 3;
  const int bid = blockIdx.x;
  const int r   = bid >> 4;        // role 0/1
  const int g   = bid & 15;        // group: partner is bid^16 (same %8 XCD class)

  __shared__ __attribute__((aligned(16))) _Float16 hfrag[16 * 64 * 8]; // 16 KB
  __shared__ float wfc[O_][H_ + 1];                                    // 32.8 KB

  // ---- resident weights: W_hh half + W_ih half as B-fragments ----
  half8 wh[64];   // [ln 0..3][kc 0..15]
  half8 wi[8];    // [ln 0..3][kc2 0..1]
  float bias[4];
  #pragma unroll
  for (int ln = 0; ln < 4; ++ln) {
    const int j = r * 256 + (w * 4 + ln) * 16 + m15;   // output dim this lane covers
    #pragma unroll
    for (int kc = 0; kc < 16; ++kc) {
      const f32x4* p = (const f32x4*)(W_hh + j * H_ + kc * 32 + q * 8);
      wh[ln * 16 + kc] = cvt_h8(p[0], p[1]);
    }
    #pragma unroll
    for (int kc = 0; kc < 2; ++kc) {
      const f32x4* p = (const f32x4*)(W_ih + j * I_ + kc * 32 + q * 8);
      wi[ln * 2 + kc] = cvt_h8(p[0], p[1]);
    }
    bias[ln] = b_ih[j] + b_hh[j];
  }

  // ---- h(0) from h0, into fragment order ----
  #pragma unroll
  for (int u = 0; u < 4; ++u) {
    const int ri = tid + u * 256;
    const int m = ri & 15, ru = ri >> 4;               // ru in [0,64): 8-run of k
    const float* p = h0 + (g * 16 + m) * H_ + ru * 8;
    _Float16* dst = &hfrag[((ru >> 2) * 64 + m + 16 * (ru & 3)) * 8];
    #pragma unroll
    for (int e = 0; e < 8; ++e) dst[e] = (_Float16)p[e];
  }
  __syncthreads();

  // x A-fragment prefetch (this lane supplies batch row m15 of the group)
  const int b_x = g * 16 + m15;
  const float* x0 = x + (b_x * T_ + 0) * I_ + q * 8;
  f32x4 xa0 = *(const f32x4*)(x0);
  f32x4 xa1 = *(const f32x4*)(x0 + 4);
  f32x4 xb0 = *(const f32x4*)(x0 + 32);
  f32x4 xb1 = *(const f32x4*)(x0 + 36);

  const int self = g * 2 + r;
  const int peer = g * 2 + (1 - r);
  int* selfflag = flags + self * 32;
  int* peerflag = flags + peer * 32;

  #pragma unroll 1
  for (int t = 0; t < T_; ++t) {
    // prefetch x for t+1 (raw fp32; converted next iteration)
    const int tn = (t + 1) & (T_ - 1);
    const float* xn = x + (b_x * T_ + tn) * I_ + q * 8;
    f32x4 na0 = *(const f32x4*)(xn);
    f32x4 na1 = *(const f32x4*)(xn + 4);
    f32x4 nb0 = *(const f32x4*)(xn + 32);
    f32x4 nb1 = *(const f32x4*)(xn + 36);

    f32x4 acc[4];
    #pragma unroll
    for (int ln = 0; ln < 4; ++ln) { acc[ln][0] = 0.f; acc[ln][1] = 0.f; acc[ln][2] = 0.f; acc[ln][3] = 0.f; }

    // x_t @ W_ih^T  (K=64)
    {
      half8 ax0 = cvt_h8(xa0, xa1);
      half8 ax1 = cvt_h8(xb0, xb1);
      #pragma unroll
      for (int ln = 0; ln < 4; ++ln) {
        acc[ln] = MFMA16(ax0, wi[ln * 2 + 0], acc[ln]);
        acc[ln] = MFMA16(ax1, wi[ln * 2 + 1], acc[ln]);
      }
    }
    // h(t) @ W_hh^T  (K=512)
    #pragma unroll
    for (int kc = 0; kc < 16; ++kc) {
      half8 a = *(const half8*)&hfrag[(kc * 64 + L) * 8];
      #pragma unroll
      for (int ln = 0; ln < 4; ++ln) acc[ln] = MFMA16(a, wh[ln * 16 + kc], acc[ln]);
    }
    __syncthreads();   // all A-reads of h(t) complete before overwrite

    // epilogue: relu(acc + bias) -> f16 scatter into own half of hfrag
    // D layout: col = lane&15 (=j offset), row = 4*q + reg (=local batch)
    #pragma unroll
    for (int ln = 0; ln < 4; ++ln) {
      const int j = r * 256 + (w * 4 + ln) * 16 + m15;
      const int base = ((j >> 5) * 64 + 16 * ((j >> 3) & 3)) * 8 + (j & 7);
      #pragma unroll
      for (int i = 0; i < 4; ++i) {
        float v = acc[ln][i] + bias[ln];
        v = fmaxf(v, 0.f);
        hfrag[base + (4 * q + i) * 8] = (_Float16)v;
      }
    }
    __syncthreads();

    // publish own half (8 KB) to parity-buffered exchange, release flag
    const int p = t & 1;
    _Float16* Xo = Xbuf + ((self * 2 + p) << 12);
    #pragma unroll
    for (int u = 0; u < 2; ++u) {
      const int ri = tid + u * 256;
      const int m = ri & 15, ru = ri >> 4;             // ru in [0,32)
      const int j0 = r * 256 + ru * 8;
      half8 v = *(const half8*)&hfrag[((j0 >> 5) * 64 + m + 16 * ((j0 >> 3) & 3)) * 8];
      *(half8*)(Xo + m * 256 + ru * 8) = v;
    }
    __threadfence();
    __syncthreads();
    if (tid == 0)
      __hip_atomic_store(selfflag, t + 1, __ATOMIC_RELEASE, __HIP_MEMORY_SCOPE_AGENT);

    // acquire partner half
    while (__hip_atomic_load(peerflag, __ATOMIC_ACQUIRE, __HIP_MEMORY_SCOPE_AGENT) < t + 1)
      __builtin_amdgcn_s_sleep(1);
    const _Float16* Xi = Xbuf + ((peer * 2 + p) << 12);
    #pragma unroll
    for (int u = 0; u < 2; ++u) {
      const int ri = tid + u * 256;
      const int m = ri & 15, ru = ri >> 4;
      const int j0 = (1 - r) * 256 + ru * 8;
      half8 v = *(const half8*)(Xi + m * 256 + ru * 8);
      *(half8*)&hfrag[((j0 >> 5) * 64 + m + 16 * ((j0 >> 3) & 3)) * 8] = v;
    }
    __syncthreads();

    xa0 = na0; xa1 = na1; xb0 = nb0; xb1 = nb1;
  }

  // ---- outputs: role 0 has full h(T) ----
  if (r == 0) {
    // output 1: h_last (1,B,H) fp32 at out+4096
    #pragma unroll
    for (int u = 0; u < 4; ++u) {
      const int ri = tid + u * 256;
      const int m = ri & 15, ru = ri >> 4;             // [0,64)
      const half8 v = *(const half8*)&hfrag[((ru >> 2) * 64 + m + 16 * (ru & 3)) * 8];
      float* dst = out + 4096 + (g * 16 + m) * H_ + ru * 8;
      #pragma unroll
      for (int e = 0; e < 8; ++e) dst[e] = (float)v[e];
    }
    // output 0: FC  out[b][o] = h_last[b] . W_fc[o] + b_fc[o]
    #pragma unroll
    for (int u = 0; u < 32; ++u) {
      const int idx = tid + u * 256;
      wfc[idx >> 9][idx & 511] = W_fc[idx];
    }
    __syncthreads();
    const int bl = tid >> 4, o = tid & 15;
    float s = 0.f;
    #pragma unroll 8
    for (int ru = 0; ru < 64; ++ru) {
      const half8 v = *(const half8*)&hfrag[((ru >> 2) * 64 + bl + 16 * (ru & 3)) * 8];
      #pragma unroll
      for (int e = 0; e < 8; ++e) s += (float)v[e] * wfc[o][ru * 8 + e];
    }
    out[(g * 16 + bl) * 16 + o] = s + b_fc[o];
  }
}

extern "C" void kernel_launch(void* const* d_in, const int* in_sizes, int n_in,
                              void* d_out, int out_size, void* d_ws, size_t ws_size,
                              hipStream_t stream) {
  const float* x    = (const float*)d_in[0];
  const float* h0   = (const float*)d_in[1];
  const float* W_ih = (const float*)d_in[2];
  const float* W_hh = (const float*)d_in[3];
  const float* b_ih = (const float*)d_in[4];
  const float* b_hh = (const float*)d_in[5];
  const float* W_fc = (const float*)d_in[6];
  const float* b_fc = (const float*)d_in[7];
  float* out = (float*)d_out;

  _Float16* Xbuf = (_Float16*)d_ws;                       // 32 groups*roles x 2 parity x 8KB = 512KB
  int* flags = (int*)((char*)d_ws + 512 * 1024);          // 32 flags, 128B stride
  hipMemsetAsync(flags, 0, 32 * 32 * sizeof(int), stream);

  rnn_persist<<<dim3(32), dim3(256), 0, stream>>>(x, h0, W_ih, W_hh, b_ih, b_hh,
                                                  W_fc, b_fc, out, Xbuf, flags);
}

// Round 2
// 1889.066 us; speedup vs baseline: 1.6366x; 1.6366x over previous
//
#include <hip/hip_runtime.h>

#define B_ 256
#define T_ 512
#define I_ 64
#define H_ 512
#define O_ 16

typedef _Float16 half8 __attribute__((ext_vector_type(8)));
typedef float    f32x4 __attribute__((ext_vector_type(4)));

#define MFMA16(a, b, c) __builtin_amdgcn_mfma_f32_16x16x32_f16((a), (b), (c), 0, 0, 0)

__device__ inline half8 cvt_h8(f32x4 a, f32x4 b) {
  half8 v;
  v[0] = (_Float16)a[0]; v[1] = (_Float16)a[1]; v[2] = (_Float16)a[2]; v[3] = (_Float16)a[3];
  v[4] = (_Float16)b[0]; v[5] = (_Float16)b[1]; v[6] = (_Float16)b[2]; v[7] = (_Float16)b[3];
  return v;
}

// One block per 16-batch group -> ZERO inter-block communication.
// 16 blocks x 256 threads (4 waves). Wave w owns output dims [128w,128w+128)
// (8 ln-tiles of 16). Weights f16: W_hh K-chunks 0..11 in VGPRs (384),
// K-chunks 12..15 in LDS (128 KB, per-thread-private slots, conflict-free
// ds_read_b128), W_ih in VGPRs (64). h(t) in LDS in MFMA A-fragment order.
__global__ __launch_bounds__(256, 1)
void rnn_persist(const float* __restrict__ x, const float* __restrict__ h0,
                 const float* __restrict__ W_ih, const float* __restrict__ W_hh,
                 const float* __restrict__ b_ih, const float* __restrict__ b_hh,
                 const float* __restrict__ W_fc, const float* __restrict__ b_fc,
                 float* __restrict__ out) {
  const int tid = threadIdx.x;
  const int L   = tid & 63;
  const int w   = tid >> 6;        // wave 0..3
  const int m15 = L & 15;
  const int q   = (L >> 4) & 3;
  const int g   = blockIdx.x;      // group: batches [16g, 16g+16)

  __shared__ __attribute__((aligned(16))) _Float16 hfrag[16 * 64 * 8];      // 16 KB
  __shared__ __attribute__((aligned(16))) _Float16 wlds[32 * 4 * 64 * 8];   // 128 KB
  half8* wl = (half8*)wlds;
  const half8* hf = (const half8*)hfrag;

  // ---- resident weights ----
  half8 whr[96];   // [ln 0..8][kc 0..12]
  half8 wi[16];    // [ln 0..8][c 0..2]
  float bias[8];
  #pragma unroll
  for (int ln = 0; ln < 8; ++ln) {
    const int j = w * 128 + ln * 16 + m15;           // output dim this lane covers
    bias[ln] = b_ih[j] + b_hh[j];
    #pragma unroll
    for (int kc = 0; kc < 12; ++kc) {
      const f32x4* p = (const f32x4*)(W_hh + j * H_ + kc * 32 + q * 8);
      whr[ln * 12 + kc] = cvt_h8(p[0], p[1]);
    }
    #pragma unroll
    for (int kc = 0; kc < 4; ++kc) {
      const f32x4* p = (const f32x4*)(W_hh + j * H_ + (12 + kc) * 32 + q * 8);
      wl[((w * 8 + ln) * 4 + kc) * 64 + L] = cvt_h8(p[0], p[1]);
    }
    #pragma unroll
    for (int c = 0; c < 2; ++c) {
      const f32x4* p = (const f32x4*)(W_ih + j * I_ + c * 32 + q * 8);
      wi[ln * 2 + c] = cvt_h8(p[0], p[1]);
    }
  }

  // ---- h(0) into fragment order: hfrag[(kc*64 + m+16*qq)*8 + e] = h[m][kc*32+qq*8+e]
  #pragma unroll
  for (int u = 0; u < 4; ++u) {
    const int ri = tid + u * 256;
    const int m = ri & 15, ru = ri >> 4;             // ru in [0,64)
    const float* p = h0 + (g * 16 + m) * H_ + ru * 8;
    _Float16* dst = &hfrag[(((ru >> 2) * 64) + m + 16 * (ru & 3)) * 8];
    #pragma unroll
    for (int e = 0; e < 8; ++e) dst[e] = (_Float16)p[e];
  }
  __syncthreads();

  // x A-fragment prefetch (lane supplies batch row m15, k = c*32 + q*8 + e)
  const int b_x = g * 16 + m15;
  const float* x0 = x + ((size_t)b_x * T_) * I_ + q * 8;
  half8 xa0, xa1;
  {
    f32x4 p0 = *(const f32x4*)(x0);
    f32x4 p1 = *(const f32x4*)(x0 + 4);
    f32x4 p2 = *(const f32x4*)(x0 + 32);
    f32x4 p3 = *(const f32x4*)(x0 + 36);
    xa0 = cvt_h8(p0, p1);
    xa1 = cvt_h8(p2, p3);
  }

  #pragma unroll 1
  for (int t = 0; t < T_; ++t) {
    // prefetch x for t+1 (kept as raw fp32 across the body to hide HBM latency)
    const int tn = (t + 1) & (T_ - 1);
    const float* xn = x + ((size_t)b_x * T_ + tn) * I_ + q * 8;
    f32x4 n0 = *(const f32x4*)(xn);
    f32x4 n1 = *(const f32x4*)(xn + 4);
    f32x4 n2 = *(const f32x4*)(xn + 32);
    f32x4 n3 = *(const f32x4*)(xn + 36);

    f32x4 acc[8];
    // x_t @ W_ih^T  (K=64)
    #pragma unroll
    for (int ln = 0; ln < 8; ++ln) {
      f32x4 z; z[0] = 0.f; z[1] = 0.f; z[2] = 0.f; z[3] = 0.f;
      acc[ln] = MFMA16(xa0, wi[ln * 2 + 0], z);
      acc[ln] = MFMA16(xa1, wi[ln * 2 + 1], acc[ln]);
    }
    // h(t) @ W_hh^T, register chunks (K = 0..384)
    #pragma unroll
    for (int kc = 0; kc < 12; ++kc) {
      const half8 a = hf[kc * 64 + L];
      #pragma unroll
      for (int ln = 0; ln < 8; ++ln) acc[ln] = MFMA16(a, whr[ln * 12 + kc], acc[ln]);
    }
    // LDS chunks (K = 384..512)
    #pragma unroll
    for (int kc = 0; kc < 4; ++kc) {
      const half8 a = hf[(12 + kc) * 64 + L];
      #pragma unroll
      for (int ln = 0; ln < 8; ++ln)
        acc[ln] = MFMA16(a, wl[((w * 8 + ln) * 4 + kc) * 64 + L], acc[ln]);
    }
    __syncthreads();   // all A-reads of h(t) complete before overwrite

    // epilogue: relu(acc + bias) -> f16 scatter into hfrag
    // D layout: col = lane&15 (j offset), row = 4*q + i (local batch)
    #pragma unroll
    for (int ln = 0; ln < 8; ++ln) {
      const int j = w * 128 + ln * 16 + m15;
      const int base = ((j >> 5) * 64 + 16 * ((j >> 3) & 3)) * 8 + (j & 7);
      #pragma unroll
      for (int i = 0; i < 4; ++i) {
        float v = acc[ln][i] + bias[ln];
        v = fmaxf(v, 0.f);
        hfrag[base + (4 * q + i) * 8] = (_Float16)v;
      }
    }
    __syncthreads();

    xa0 = cvt_h8(n0, n1);
    xa1 = cvt_h8(n2, n3);
  }

  // ---- outputs ----
  // output 1: h_last (1,B,H) fp32 at out+4096
  #pragma unroll
  for (int u = 0; u < 4; ++u) {
    const int ri = tid + u * 256;
    const int m = ri & 15, ru = ri >> 4;             // [0,64)
    const half8 v = hf[((ru >> 2) * 64) + ((m + 16 * (ru & 3)) >> 0)];
    // note: hf index = (ru>>2)*64 + m + 16*(ru&3)
    float* dst = out + 4096 + (g * 16 + m) * H_ + ru * 8;
    #pragma unroll
    for (int e = 0; e < 8; ++e) dst[e] = (float)v[e];
  }
  // output 0: FC. Reuse wlds LDS as fp32 W_fc tile [16][513].
  __syncthreads();
  float* wfcf = (float*)wlds;
  #pragma unroll
  for (int u = 0; u < 32; ++u) {
    const int idx = tid + u * 256;
    wfcf[(idx >> 9) * 513 + (idx & 511)] = W_fc[idx];
  }
  __syncthreads();
  const int bl = tid >> 4, o = tid & 15;
  float s = 0.f;
  #pragma unroll 8
  for (int ru = 0; ru < 64; ++ru) {
    const half8 v = hf[((ru >> 2) * 64) + bl + 16 * (ru & 3)];
    #pragma unroll
    for (int e = 0; e < 8; ++e) s += (float)v[e] * wfcf[o * 513 + ru * 8 + e];
  }
  out[(g * 16 + bl) * 16 + o] = s + b_fc[o];
}

extern "C" void kernel_launch(void* const* d_in, const int* in_sizes, int n_in,
                              void* d_out, int out_size, void* d_ws, size_t ws_size,
                              hipStream_t stream) {
  const float* x    = (const float*)d_in[0];
  const float* h0   = (const float*)d_in[1];
  const float* W_ih = (const float*)d_in[2];
  const float* W_hh = (const float*)d_in[3];
  const float* b_ih = (const float*)d_in[4];
  const float* b_hh = (const float*)d_in[5];
  const float* W_fc = (const float*)d_in[6];
  const float* b_fc = (const float*)d_in[7];
  float* out = (float*)d_out;

  rnn_persist<<<dim3(16), dim3(256), 0, stream>>>(x, h0, W_ih, W_hh, b_ih, b_hh,
                                                  W_fc, b_fc, out);
}

// Round 3
// 1394.533 us; speedup vs baseline: 2.2169x; 1.3546x over previous
//
#include <hip/hip_runtime.h>

#define B_ 256
#define T_ 512
#define I_ 64
#define H_ 512
#define O_ 16

typedef _Float16 half8 __attribute__((ext_vector_type(8)));
typedef _Float16 half4 __attribute__((ext_vector_type(4)));
typedef float    f32x4 __attribute__((ext_vector_type(4)));

#define MFMA16(a, b, c) __builtin_amdgcn_mfma_f32_16x16x32_f16((a), (b), (c), 0, 0, 0)

__device__ inline half8 cvt_h8(f32x4 a, f32x4 b) {
  half8 v;
  v[0] = (_Float16)a[0]; v[1] = (_Float16)a[1]; v[2] = (_Float16)a[2]; v[3] = (_Float16)a[3];
  v[4] = (_Float16)b[0]; v[5] = (_Float16)b[1]; v[6] = (_Float16)b[2]; v[7] = (_Float16)b[3];
  return v;
}

// ---------------- prepass: xp[t,b,j] = x[b,t,:] @ W_ih^T + b_ih + b_hh ----------------
// Stored f16 in the EXACT per-thread order the main loop consumes:
// slot addr = ((t*16+g)*512 + tid_c)*16 + ln*4 + i, where consumer thread
// tid_c = w_c*64 + q*16 + m15 covers j = w_c*64 + ln*16 + m15, batch = g*16 + 4q+i.
__global__ __launch_bounds__(256, 2)
void xp_prepass(const float* __restrict__ x, const float* __restrict__ W_ih,
                const float* __restrict__ b_ih, const float* __restrict__ b_hh,
                _Float16* __restrict__ xp) {
  const int tid = threadIdx.x, L = tid & 63, w = tid >> 6;
  const int m15 = L & 15, q = (L >> 4) & 3;
  const int g = blockIdx.x & 15, tc = blockIdx.x >> 4;   // 512 blocks = 16 g x 32 tc

  // A-frags: rows = batches (m15), one tile per t; K = I = 64 -> 2 chunks
  half8 a[4][2];
  #pragma unroll
  for (int rr = 0; rr < 4; ++rr) {
    const int t = tc * 16 + w * 4 + rr;
    const float* p = x + ((size_t)(g * 16 + m15) * T_ + t) * I_ + q * 8;
    a[rr][0] = cvt_h8(*(const f32x4*)(p),      *(const f32x4*)(p + 4));
    a[rr][1] = cvt_h8(*(const f32x4*)(p + 32), *(const f32x4*)(p + 36));
  }
  #pragma unroll 1
  for (int jt = 0; jt < 32; ++jt) {
    const int j = jt * 16 + m15;
    const float* wp = W_ih + j * I_ + q * 8;
    const half8 b0 = cvt_h8(*(const f32x4*)(wp),      *(const f32x4*)(wp + 4));
    const half8 b1 = cvt_h8(*(const f32x4*)(wp + 32), *(const f32x4*)(wp + 36));
    const float bias = b_ih[j] + b_hh[j];
    #pragma unroll
    for (int rr = 0; rr < 4; ++rr) {
      const int t = tc * 16 + w * 4 + rr;
      f32x4 acc; acc[0] = 0.f; acc[1] = 0.f; acc[2] = 0.f; acc[3] = 0.f;
      acc = MFMA16(a[rr][0], b0, acc);
      acc = MFMA16(a[rr][1], b1, acc);
      half4 hv;
      #pragma unroll
      for (int i = 0; i < 4; ++i) hv[i] = (_Float16)(acc[i] + bias);
      // D-layout: col=m15 (j), row=4q+i (batch) -> matches consumer slot mapping
      _Float16* dst = xp + ((size_t)((t * 16 + g) * 512 + (jt >> 2) * 64 + q * 16 + m15)) * 16
                         + (jt & 3) * 4;
      *(half4*)dst = hv;
    }
  }
}

// ---------------- main persistent RNN ----------------
// 16 blocks x 512 threads (8 waves, 2/SIMD). Wave w owns j in [64w, 64w+64)
// (4 ln-tiles). Per-thread weights: 12 K-chunks in VGPRs (192 regs), 4 K-chunks
// in LDS (128 KB). h(t) in LDS in MFMA A-fragment order (conflict-free b128).
// xp gives acc-init per step: 32 B/thread contiguous.
__global__ __launch_bounds__(512, 2)
void rnn_persist(const float* __restrict__ x, const float* __restrict__ h0,
                 const float* __restrict__ W_ih, const float* __restrict__ W_hh,
                 const float* __restrict__ b_ih, const float* __restrict__ b_hh,
                 const float* __restrict__ W_fc, const float* __restrict__ b_fc,
                 float* __restrict__ out, const _Float16* __restrict__ xp) {
  const int tid = threadIdx.x;
  const int L   = tid & 63;
  const int w   = tid >> 6;        // wave 0..7
  const int m15 = L & 15;
  const int q   = (L >> 4) & 3;
  const int g   = blockIdx.x;      // batches [16g, 16g+16)
  const bool use_xp = (xp != nullptr);

  __shared__ __attribute__((aligned(16))) _Float16 hfrag[16 * 64 * 8];      // 16 KB
  __shared__ __attribute__((aligned(16))) _Float16 wlds[32 * 4 * 64 * 8];   // 128 KB
  half8* wl = (half8*)wlds;
  const half8* hf = (const half8*)hfrag;

  // ---- resident weights: W_hh, K-chunks 0..11 regs / 12..15 LDS ----
  half8 whr[48];   // [ln 0..4][kc 0..12] -> 192 VGPRs
  float bias[4];
  #pragma unroll
  for (int ln = 0; ln < 4; ++ln) {
    const int j = w * 64 + ln * 16 + m15;
    bias[ln] = use_xp ? 0.f : (b_ih[j] + b_hh[j]);   // xp path has bias folded in
    #pragma unroll
    for (int kc = 0; kc < 12; ++kc) {
      const f32x4* p = (const f32x4*)(W_hh + j * H_ + kc * 32 + q * 8);
      whr[ln * 12 + kc] = cvt_h8(p[0], p[1]);
    }
    #pragma unroll
    for (int kc = 0; kc < 4; ++kc) {
      const f32x4* p = (const f32x4*)(W_hh + j * H_ + (12 + kc) * 32 + q * 8);
      wl[((w * 4 + ln) * 4 + kc) * 64 + L] = cvt_h8(p[0], p[1]);
    }
  }

  // ---- h(0) into fragment order ----
  #pragma unroll
  for (int u = 0; u < 2; ++u) {
    const int ri = tid + u * 512;                    // [0,1024)
    const int m = ri & 15, ru = ri >> 4;             // ru in [0,64)
    const float* p = h0 + (g * 16 + m) * H_ + ru * 8;
    _Float16* dst = &hfrag[(((ru >> 2) * 64) + m + 16 * (ru & 3)) * 8];
    #pragma unroll
    for (int e = 0; e < 8; ++e) dst[e] = (_Float16)p[e];
  }
  __syncthreads();

  // xp prefetch for t=0 (32 B/thread)
  half8 xq0, xq1;
  if (use_xp) {
    const _Float16* p0 = xp + ((size_t)(0 * 16 + g) * 512 + tid) * 16;
    xq0 = ((const half8*)p0)[0];
    xq1 = ((const half8*)p0)[1];
  }

  #pragma unroll 1
  for (int t = 0; t < T_; ++t) {
    f32x4 acc[4];
    if (use_xp) {
      #pragma unroll
      for (int ln = 0; ln < 4; ++ln)
        #pragma unroll
        for (int i = 0; i < 4; ++i)
          acc[ln][i] = (float)((ln < 2 ? xq0 : xq1)[(ln & 1) * 4 + i]);
    } else {
      // fallback: inline x-projection (streamed W_ih from L2)
      const float* p = x + ((size_t)(g * 16 + m15) * T_ + t) * I_ + q * 8;
      const half8 ax0 = cvt_h8(*(const f32x4*)(p),      *(const f32x4*)(p + 4));
      const half8 ax1 = cvt_h8(*(const f32x4*)(p + 32), *(const f32x4*)(p + 36));
      #pragma unroll
      for (int ln = 0; ln < 4; ++ln) {
        const int j = w * 64 + ln * 16 + m15;
        const float* wp = W_ih + j * I_ + q * 8;
        const half8 b0 = cvt_h8(*(const f32x4*)(wp),      *(const f32x4*)(wp + 4));
        const half8 b1 = cvt_h8(*(const f32x4*)(wp + 32), *(const f32x4*)(wp + 36));
        f32x4 z; z[0] = 0.f; z[1] = 0.f; z[2] = 0.f; z[3] = 0.f;
        acc[ln] = MFMA16(ax0, b0, z);
        acc[ln] = MFMA16(ax1, b1, acc[ln]);
      }
    }

    // prefetch xp for t+1 (issued early; consumed after the MFMA wall)
    half8 nx0, nx1;
    if (use_xp) {
      const int tn = (t + 1) & (T_ - 1);
      const _Float16* pn = xp + ((size_t)(tn * 16 + g) * 512 + tid) * 16;
      nx0 = ((const half8*)pn)[0];
      nx1 = ((const half8*)pn)[1];
    }

    // h(t) @ W_hh^T : register chunks
    #pragma unroll
    for (int kc = 0; kc < 12; ++kc) {
      const half8 a = hf[kc * 64 + L];
      #pragma unroll
      for (int ln = 0; ln < 4; ++ln) acc[ln] = MFMA16(a, whr[ln * 12 + kc], acc[ln]);
    }
    // LDS chunks
    #pragma unroll
    for (int kc = 0; kc < 4; ++kc) {
      const half8 a = hf[(12 + kc) * 64 + L];
      #pragma unroll
      for (int ln = 0; ln < 4; ++ln)
        acc[ln] = MFMA16(a, wl[((w * 4 + ln) * 4 + kc) * 64 + L], acc[ln]);
    }
    __syncthreads();   // all A-reads of h(t) done before overwrite

    // epilogue: relu -> f16 scatter into hfrag (D: col=j=lane&15-tile, row=4q+i)
    #pragma unroll
    for (int ln = 0; ln < 4; ++ln) {
      const int j = w * 64 + ln * 16 + m15;
      const int base = ((j >> 5) * 64 + 16 * ((j >> 3) & 3)) * 8 + (j & 7);
      #pragma unroll
      for (int i = 0; i < 4; ++i) {
        float v = acc[ln][i] + bias[ln];
        v = fmaxf(v, 0.f);
        hfrag[base + (4 * q + i) * 8] = (_Float16)v;
      }
    }
    __syncthreads();

    xq0 = nx0; xq1 = nx1;
  }

  // ---- output 1: h_last (1,B,H) fp32 at out+4096 ----
  #pragma unroll
  for (int u = 0; u < 2; ++u) {
    const int ri = tid + u * 512;
    const int m = ri & 15, ru = ri >> 4;
    const half8 v = hf[((ru >> 2) * 64) + m + 16 * (ru & 3)];
    float* dst = out + 4096 + (g * 16 + m) * H_ + ru * 8;
    #pragma unroll
    for (int e = 0; e < 8; ++e) dst[e] = (float)v[e];
  }
  // ---- output 0: FC (reuse wlds as fp32 [16][513]) ----
  __syncthreads();
  float* wfcf = (float*)wlds;
  #pragma unroll
  for (int u = 0; u < 16; ++u) {
    const int idx = tid + u * 512;
    wfcf[(idx >> 9) * 513 + (idx & 511)] = W_fc[idx];
  }
  __syncthreads();
  if (tid < 256) {
    const int bl = tid >> 4, o = tid & 15;
    float s = 0.f;
    #pragma unroll 8
    for (int ru = 0; ru < 64; ++ru) {
      const half8 v = hf[((ru >> 2) * 64) + bl + 16 * (ru & 3)];
      #pragma unroll
      for (int e = 0; e < 8; ++e) s += (float)v[e] * wfcf[o * 513 + ru * 8 + e];
    }
    out[(g * 16 + bl) * 16 + o] = s + b_fc[o];
  }
}

extern "C" void kernel_launch(void* const* d_in, const int* in_sizes, int n_in,
                              void* d_out, int out_size, void* d_ws, size_t ws_size,
                              hipStream_t stream) {
  const float* x    = (const float*)d_in[0];
  const float* h0   = (const float*)d_in[1];
  const float* W_ih = (const float*)d_in[2];
  const float* W_hh = (const float*)d_in[3];
  const float* b_ih = (const float*)d_in[4];
  const float* b_hh = (const float*)d_in[5];
  const float* W_fc = (const float*)d_in[6];
  const float* b_fc = (const float*)d_in[7];
  float* out = (float*)d_out;

  const size_t XP_BYTES = (size_t)B_ * T_ * H_ * 2;   // 134 MB f16
  _Float16* xp = (ws_size >= XP_BYTES) ? (_Float16*)d_ws : nullptr;

  if (xp)
    xp_prepass<<<dim3(512), dim3(256), 0, stream>>>(x, W_ih, b_ih, b_hh, xp);
  rnn_persist<<<dim3(16), dim3(512), 0, stream>>>(x, h0, W_ih, W_hh, b_ih, b_hh,
                                                  W_fc, b_fc, out, xp);
}

// Round 5
// 1296.033 us; speedup vs baseline: 2.3854x; 1.0760x over previous
//
#include <hip/hip_runtime.h>

#define B_ 256
#define T_ 512
#define I_ 64
#define H_ 512
#define O_ 16

typedef _Float16 half8 __attribute__((ext_vector_type(8)));
typedef _Float16 half4 __attribute__((ext_vector_type(4)));
typedef float    f32x4 __attribute__((ext_vector_type(4)));

#define MFMA16(a, b, c) __builtin_amdgcn_mfma_f32_16x16x32_f16((a), (b), (c), 0, 0, 0)

__device__ inline half8 cvt_h8(f32x4 a, f32x4 b) {
  half8 v;
  v[0] = (_Float16)a[0]; v[1] = (_Float16)a[1]; v[2] = (_Float16)a[2]; v[3] = (_Float16)a[3];
  v[4] = (_Float16)b[0]; v[5] = (_Float16)b[1]; v[6] = (_Float16)b[2]; v[7] = (_Float16)b[3];
  return v;
}

// ---------------- prepass: xp[t,b,j] = x[b,t,:] @ W_ih^T + b_ih + b_hh ----------------
// f16, stored in the EXACT per-thread order the 256-thread main loop consumes:
// consumer thread tid_c = w_c*64 + q*16 + m15 covers j = w_c*128 + ln*16 + m15
// (ln 0..7), batch = g*16 + 4q+i. Slot (halves) =
//   ((t*16+g)*256 + tid_c)*32 + ln*4 + i.
__global__ __launch_bounds__(256, 2)
void xp_prepass(const float* __restrict__ x, const float* __restrict__ W_ih,
                const float* __restrict__ b_ih, const float* __restrict__ b_hh,
                _Float16* __restrict__ xp) {
  const int tid = threadIdx.x, L = tid & 63, w = tid >> 6;
  const int m15 = L & 15, q = (L >> 4) & 3;
  const int g = blockIdx.x & 15, tc = blockIdx.x >> 4;   // 512 blocks = 16 g x 32 tc

  half8 a[4][2];
  #pragma unroll
  for (int rr = 0; rr < 4; ++rr) {
    const int t = tc * 16 + w * 4 + rr;
    const float* p = x + ((size_t)(g * 16 + m15) * T_ + t) * I_ + q * 8;
    a[rr][0] = cvt_h8(*(const f32x4*)(p),      *(const f32x4*)(p + 4));
    a[rr][1] = cvt_h8(*(const f32x4*)(p + 32), *(const f32x4*)(p + 36));
  }
  #pragma unroll 1
  for (int jt = 0; jt < 32; ++jt) {
    const int j = jt * 16 + m15;
    const float* wp = W_ih + j * I_ + q * 8;
    const half8 b0 = cvt_h8(*(const f32x4*)(wp),      *(const f32x4*)(wp + 4));
    const half8 b1 = cvt_h8(*(const f32x4*)(wp + 32), *(const f32x4*)(wp + 36));
    const float bias = b_ih[j] + b_hh[j];
    #pragma unroll
    for (int rr = 0; rr < 4; ++rr) {
      const int t = tc * 16 + w * 4 + rr;
      f32x4 acc; acc[0] = 0.f; acc[1] = 0.f; acc[2] = 0.f; acc[3] = 0.f;
      acc = MFMA16(a[rr][0], b0, acc);
      acc = MFMA16(a[rr][1], b1, acc);
      half4 hv;
      #pragma unroll
      for (int i = 0; i < 4; ++i) hv[i] = (_Float16)(acc[i] + bias);
      // D-layout: col=m15 (j), row=4q+i (batch). Consumer: wave jt>>3, ln jt&7.
      _Float16* dst = xp + ((size_t)((t * 16 + g) * 256 + (jt >> 3) * 64 + q * 16 + m15)) * 32
                         + (jt & 7) * 4;
      *(half4*)dst = hv;
    }
  }
}

// ---------------- main persistent RNN ----------------
// 16 blocks x 256 threads (4 waves, 1/SIMD, 512-reg budget). Wave w owns
// j in [128w, 128w+128) (8 ln-tiles). W_hh per wave: kc 0..7 pinned into
// AGPRs (256, via empty-asm class pin; MFMAs stay BUILTIN — gfx950 MFMA reads
// AGPR sources directly), kc 8..11 in arch VGPRs (128), kc 12..15 in LDS
// (128 KB). h(t) in LDS in MFMA A-fragment order (conflict-free ds_read_b128).
__global__ __launch_bounds__(256, 1)
void rnn_persist(const float* __restrict__ h0, const float* __restrict__ W_hh,
                 const float* __restrict__ W_fc, const float* __restrict__ b_fc,
                 float* __restrict__ out, const _Float16* __restrict__ xp) {
  const int tid = threadIdx.x;
  const int L   = tid & 63;
  const int w   = tid >> 6;        // wave 0..3
  const int m15 = L & 15;
  const int q   = (L >> 4) & 3;
  const int g   = blockIdx.x;      // batches [16g, 16g+16)

  __shared__ __attribute__((aligned(16))) _Float16 hfrag[16 * 64 * 8];      // 16 KB
  __shared__ __attribute__((aligned(16))) _Float16 wlds[128 * 64 * 8];      // 128 KB
  half8* wl = (half8*)wlds;
  const half8* hf = (const half8*)hfrag;

  // ---- resident weights ----
  half8 whA[64];   // [ln 0..8][kc 0..8]  -> 256 AGPR (class-pinned below)
  half8 whV[32];   // [ln 0..8][kc 0..4]  -> 128 arch VGPR
  #pragma unroll
  for (int ln = 0; ln < 8; ++ln) {
    const int j = w * 128 + ln * 16 + m15;
    #pragma unroll
    for (int kc = 0; kc < 8; ++kc) {
      const f32x4* p = (const f32x4*)(W_hh + j * H_ + kc * 32 + q * 8);
      whA[ln * 8 + kc] = cvt_h8(p[0], p[1]);
    }
    #pragma unroll
    for (int kc = 0; kc < 4; ++kc) {
      const f32x4* p = (const f32x4*)(W_hh + j * H_ + (8 + kc) * 32 + q * 8);
      whV[ln * 4 + kc] = cvt_h8(p[0], p[1]);
    }
    #pragma unroll
    for (int kc = 0; kc < 4; ++kc) {
      const f32x4* p = (const f32x4*)(W_hh + j * H_ + (12 + kc) * 32 + q * 8);
      wl[((w * 8 + ln) * 4 + kc) * 64 + L] = cvt_h8(p[0], p[1]);
    }
  }
  // One-time AGPR class pin: forces whA into accumulator regs; zero per-step
  // cost, all MFMAs remain builtins (hazards/waitcnts fully compiler-handled).
  #pragma unroll
  for (int i2 = 0; i2 < 64; ++i2) asm volatile("" : "+a"(whA[i2]));

  // ---- h(0) into fragment order: hfrag[((k>>5)*64 + m + 16*((k>>3)&3))*8 + (k&7)] ----
  #pragma unroll
  for (int u = 0; u < 4; ++u) {
    const int ri = tid + u * 256;                    // [0,1024)
    const int m = ri & 15, ru = ri >> 4;             // ru in [0,64)
    const float* p = h0 + (g * 16 + m) * H_ + ru * 8;
    _Float16* dst = &hfrag[(((ru >> 2) * 64) + m + 16 * (ru & 3)) * 8];
    #pragma unroll
    for (int e = 0; e < 8; ++e) dst[e] = (_Float16)p[e];
  }
  __syncthreads();

  // xp prefetch for t=0 (64 B/thread)
  half8 xq[4];
  {
    const half8* p0 = (const half8*)(xp + ((size_t)(0 * 16 + g) * 256 + tid) * 32);
    #pragma unroll
    for (int e = 0; e < 4; ++e) xq[e] = p0[e];
  }

  #pragma unroll 1
  for (int t = 0; t < T_; ++t) {
    // acc init from xp (bias + x-projection folded in)
    f32x4 acc[8];
    #pragma unroll
    for (int ln = 0; ln < 8; ++ln)
      #pragma unroll
      for (int i = 0; i < 4; ++i)
        acc[ln][i] = (float)(xq[ln >> 1][(ln & 1) * 4 + i]);

    // prefetch xp for t+1 (in flight across the MFMA wall)
    half8 nxq[4];
    {
      const int tn = (t + 1) & (T_ - 1);
      const half8* pn = (const half8*)(xp + ((size_t)(tn * 16 + g) * 256 + tid) * 32);
      #pragma unroll
      for (int e = 0; e < 4; ++e) nxq[e] = pn[e];
    }

    // h(t) @ W_hh^T — all builtin MFMAs
    #pragma unroll
    for (int kc = 0; kc < 8; ++kc) {
      const half8 a = hf[kc * 64 + L];
      #pragma unroll
      for (int ln = 0; ln < 8; ++ln) acc[ln] = MFMA16(a, whA[ln * 8 + kc], acc[ln]);
    }
    #pragma unroll
    for (int kc = 0; kc < 4; ++kc) {
      const half8 a = hf[(8 + kc) * 64 + L];
      #pragma unroll
      for (int ln = 0; ln < 8; ++ln) acc[ln] = MFMA16(a, whV[ln * 4 + kc], acc[ln]);
    }
    #pragma unroll
    for (int kc = 0; kc < 4; ++kc) {
      const half8 a = hf[(12 + kc) * 64 + L];
      #pragma unroll
      for (int ln = 0; ln < 8; ++ln)
        acc[ln] = MFMA16(a, wl[((w * 8 + ln) * 4 + kc) * 64 + L], acc[ln]);
    }
    __syncthreads();   // all A-reads of h(t) done before overwrite

    // epilogue: relu -> f16 scatter into hfrag (D: col=j, row=4q+i)
    #pragma unroll
    for (int ln = 0; ln < 8; ++ln) {
      const int j = w * 128 + ln * 16 + m15;
      const int base = ((j >> 5) * 64 + 16 * ((j >> 3) & 3)) * 8 + (j & 7);
      #pragma unroll
      for (int i = 0; i < 4; ++i) {
        float v = fmaxf(acc[ln][i], 0.f);
        hfrag[base + (4 * q + i) * 8] = (_Float16)v;
      }
    }
    __syncthreads();

    #pragma unroll
    for (int e = 0; e < 4; ++e) xq[e] = nxq[e];
  }

  // ---- output 1: h_last (1,B,H) fp32 at out+4096 ----
  #pragma unroll
  for (int u = 0; u < 4; ++u) {
    const int ri = tid + u * 256;
    const int m = ri & 15, ru = ri >> 4;
    const half8 v = hf[((ru >> 2) * 64) + m + 16 * (ru & 3)];
    float* dst = out + 4096 + (g * 16 + m) * H_ + ru * 8;
    #pragma unroll
    for (int e = 0; e < 8; ++e) dst[e] = (float)v[e];
  }
  // ---- output 0: FC (reuse wlds as fp32 [16][513]) ----
  __syncthreads();
  float* wfcf = (float*)wlds;
  #pragma unroll
  for (int u = 0; u < 32; ++u) {
    const int idx = tid + u * 256;
    wfcf[(idx >> 9) * 513 + (idx & 511)] = W_fc[idx];
  }
  __syncthreads();
  {
    const int bl = tid >> 4, o = tid & 15;
    float s = 0.f;
    #pragma unroll 8
    for (int ru = 0; ru < 64; ++ru) {
      const half8 v = hf[((ru >> 2) * 64) + bl + 16 * (ru & 3)];
      #pragma unroll
      for (int e = 0; e < 8; ++e) s += (float)v[e] * wfcf[o * 513 + ru * 8 + e];
    }
    out[(g * 16 + bl) * 16 + o] = s + b_fc[o];
  }
}

extern "C" void kernel_launch(void* const* d_in, const int* in_sizes, int n_in,
                              void* d_out, int out_size, void* d_ws, size_t ws_size,
                              hipStream_t stream) {
  const float* x    = (const float*)d_in[0];
  const float* h0   = (const float*)d_in[1];
  const float* W_ih = (const float*)d_in[2];
  const float* W_hh = (const float*)d_in[3];
  const float* b_ih = (const float*)d_in[4];
  const float* b_hh = (const float*)d_in[5];
  const float* W_fc = (const float*)d_in[6];
  const float* b_fc = (const float*)d_in[7];
  float* out = (float*)d_out;

  _Float16* xp = (_Float16*)d_ws;   // 134 MB f16 workspace

  xp_prepass<<<dim3(512), dim3(256), 0, stream>>>(x, W_ih, b_ih, b_hh, xp);
  rnn_persist<<<dim3(16), dim3(256), 0, stream>>>(h0, W_hh, W_fc, b_fc, out, xp);
}

// Round 6
// 1198.806 us; speedup vs baseline: 2.5789x; 1.0811x over previous
//
#include <hip/hip_runtime.h>

#define B_ 256
#define T_ 512
#define I_ 64
#define H_ 512
#define O_ 16

typedef _Float16 half8 __attribute__((ext_vector_type(8)));
typedef _Float16 half4 __attribute__((ext_vector_type(4)));
typedef float    f32x4 __attribute__((ext_vector_type(4)));

#define MFMA16(a, b, c) __builtin_amdgcn_mfma_f32_16x16x32_f16((a), (b), (c), 0, 0, 0)

__device__ inline half8 cvt_h8(f32x4 a, f32x4 b) {
  half8 v;
  v[0] = (_Float16)a[0]; v[1] = (_Float16)a[1]; v[2] = (_Float16)a[2]; v[3] = (_Float16)a[3];
  v[4] = (_Float16)b[0]; v[5] = (_Float16)b[1]; v[6] = (_Float16)b[2]; v[7] = (_Float16)b[3];
  return v;
}

// ---------------- prepass: xp = W_ih @ x_t^T + b  (D-layout: col=batch, row=j) ----
// A = W_ih (lane&15 = j-local, k-run (lane>>4)*8), B = x (lane&15 = batch).
// Stored f16 in EXACT consumer order: half-index
//   ((t*16+g)*256 + (jt>>3)*64 + lane)*32 + (jt&7)*4 + i
__global__ __launch_bounds__(256, 2)
void xp_prepass(const float* __restrict__ x, const float* __restrict__ W_ih,
                const float* __restrict__ b_ih, const float* __restrict__ b_hh,
                _Float16* __restrict__ xp) {
  const int tid = threadIdx.x, L = tid & 63, w = tid >> 6;
  const int n = L & 15, kq = (L >> 4) & 3;
  const int g = blockIdx.x & 15, tc = blockIdx.x >> 4;   // 512 blocks = 16 g x 32 tc

  __shared__ __attribute__((aligned(16))) _Float16 wlih[32 * 2 * 64 * 8]; // 64 KB A-frags
  __shared__ float biasl[512];
  const half8* wlih8 = (const half8*)wlih;

  // stage W_ih as A-fragments: slot s = (jt*2+c)*64 + L'
  #pragma unroll
  for (int u = 0; u < 16; ++u) {
    const int s = tid + u * 256;                 // [0,4096)
    const int jt = s >> 7, c = (s >> 6) & 1, Lp = s & 63;
    const int jl = Lp & 15, kq2 = Lp >> 4;
    const float* p = W_ih + (jt * 16 + jl) * I_ + c * 32 + kq2 * 8;
    ((half8*)wlih)[s] = cvt_h8(*(const f32x4*)(p), *(const f32x4*)(p + 4));
  }
  #pragma unroll
  for (int u = 0; u < 2; ++u) {
    const int idx = tid + u * 256;
    biasl[idx] = b_ih[idx] + b_hh[idx];
  }
  __syncthreads();

  // x B-fragments for this wave's 4 timesteps
  half8 xb[4][2];
  #pragma unroll
  for (int rr = 0; rr < 4; ++rr) {
    const int t = tc * 16 + w * 4 + rr;
    const float* p = x + ((size_t)(g * 16 + n) * T_ + t) * I_ + kq * 8;
    xb[rr][0] = cvt_h8(*(const f32x4*)(p),      *(const f32x4*)(p + 4));
    xb[rr][1] = cvt_h8(*(const f32x4*)(p + 32), *(const f32x4*)(p + 36));
  }

  #pragma unroll 2
  for (int jt = 0; jt < 32; ++jt) {
    const half8 a0 = wlih8[(jt * 2 + 0) * 64 + L];
    const half8 a1 = wlih8[(jt * 2 + 1) * 64 + L];
    const f32x4 bv = *(const f32x4*)&biasl[jt * 16 + 4 * kq];  // bias for rows 4kq+i
    #pragma unroll
    for (int rr = 0; rr < 4; ++rr) {
      const int t = tc * 16 + w * 4 + rr;
      f32x4 acc; acc[0] = 0.f; acc[1] = 0.f; acc[2] = 0.f; acc[3] = 0.f;
      acc = MFMA16(a0, xb[rr][0], acc);
      acc = MFMA16(a1, xb[rr][1], acc);
      half4 hv;
      #pragma unroll
      for (int i = 0; i < 4; ++i) hv[i] = (_Float16)(acc[i] + bv[i]);
      _Float16* dst = xp + ((size_t)(t * 16 + g) * 256 + (jt >> 3) * 64 + L) * 32
                         + (jt & 7) * 4;
      *(half4*)dst = hv;
    }
  }
}

// ---------------- main persistent RNN (orientation-swapped) ----------------
// 16 blocks x 256 threads (4 waves, 1/SIMD). Wave w owns j in [128w,128w+128).
// A = W_hh fragments: kc 0..7 AGPR (pinned), kc 8..12 VGPR, kc 13..15 LDS.
// B = h in LDS B-frag layout, DOUBLE-BUFFERED: half8 slot = buf*1024 + kc*64 + L.
// Epilogue: D(col=batch,row=j) -> 8 ds_write_b64 (4 consecutive j = next step's
// K dim), 2-way bank conflict = free. ONE barrier per step.
__global__ __launch_bounds__(256, 1)
void rnn_persist(const float* __restrict__ h0, const float* __restrict__ W_hh,
                 const float* __restrict__ W_fc, const float* __restrict__ b_fc,
                 float* __restrict__ out, const _Float16* __restrict__ xp) {
  const int tid = threadIdx.x;
  const int L   = tid & 63;
  const int w   = tid >> 6;        // wave 0..3
  const int n   = L & 15;          // batch col (B/D) or j-local (A)
  const int kq  = (L >> 4) & 3;
  const int g   = blockIdx.x;      // batches [16g, 16g+16)

  __shared__ __attribute__((aligned(16))) _Float16 hb[2 * 16 * 64 * 8];     // 32 KB
  __shared__ __attribute__((aligned(16))) _Float16 wlds[4 * 8 * 3 * 64 * 8];// 96 KB
  const half8* wl = (const half8*)wlds;
  half8* wlw = (half8*)wlds;

  // ---- resident W_hh A-fragments (lane: j = w*128 + ln*16 + n, k-run kq*8) ----
  half8 whA[64];   // kc 0..7  -> 256 AGPR (class-pinned)
  half8 whV[40];   // kc 8..12 -> 160 arch VGPR
  #pragma unroll
  for (int ln = 0; ln < 8; ++ln) {
    const int j = w * 128 + ln * 16 + n;
    #pragma unroll
    for (int kc = 0; kc < 8; ++kc) {
      const f32x4* p = (const f32x4*)(W_hh + j * H_ + kc * 32 + kq * 8);
      whA[ln * 8 + kc] = cvt_h8(p[0], p[1]);
    }
    #pragma unroll
    for (int kc = 0; kc < 5; ++kc) {
      const f32x4* p = (const f32x4*)(W_hh + j * H_ + (8 + kc) * 32 + kq * 8);
      whV[ln * 5 + kc] = cvt_h8(p[0], p[1]);
    }
    #pragma unroll
    for (int kc = 0; kc < 3; ++kc) {
      const f32x4* p = (const f32x4*)(W_hh + j * H_ + (13 + kc) * 32 + kq * 8);
      wlw[((w * 8 + ln) * 3 + kc) * 64 + L] = cvt_h8(p[0], p[1]);
    }
  }
  // One-time AGPR class pin (all MFMAs stay builtins; hazards compiler-handled).
  #pragma unroll
  for (int i2 = 0; i2 < 64; ++i2) asm volatile("" : "+a"(whA[i2]));

  // ---- h(0) into B-layout buffer 0: slot S = k8*16 + nb ----
  #pragma unroll
  for (int u = 0; u < 4; ++u) {
    const int S = tid + u * 256;                 // [0,1024)
    const int k8 = S >> 4, nb = S & 15;
    const float* p = h0 + (g * 16 + nb) * H_ + k8 * 8;
    ((half8*)hb)[S] = cvt_h8(*(const f32x4*)(p), *(const f32x4*)(p + 4));
  }
  __syncthreads();

  // xp for t=0 (4 x half8 per thread)
  half8 xq[4];
  {
    const half8* p0 = (const half8*)(xp + ((size_t)(0 * 16 + g) * 256 + tid) * 32);
    #pragma unroll
    for (int e = 0; e < 4; ++e) xq[e] = p0[e];
  }

  #pragma unroll 1
  for (int t = 0; t < T_; ++t) {
    const half8* hbr = (const half8*)hb + (t & 1) * 1024;
    _Float16* hbw = hb + (((t + 1) & 1) * 1024) * 8;

    // acc init from xp: acc[ln][i] for row j = w*128 + ln*16 + 4kq + i, col n
    f32x4 acc[8];
    #pragma unroll
    for (int ln = 0; ln < 8; ++ln)
      #pragma unroll
      for (int i = 0; i < 4; ++i)
        acc[ln][i] = (float)(xq[ln >> 1][(ln & 1) * 4 + i]);

    // reload xq for t+1 (WAR on xq; load hidden behind the MFMA wall)
    {
      const int tn = (t + 1) & (T_ - 1);
      const half8* pn = (const half8*)(xp + ((size_t)(tn * 16 + g) * 256 + tid) * 32);
      #pragma unroll
      for (int e = 0; e < 4; ++e) xq[e] = pn[e];
    }

    // MFMA wall: A = weights, B = h
    #pragma unroll
    for (int kc = 0; kc < 8; ++kc) {
      const half8 b = hbr[kc * 64 + L];
      #pragma unroll
      for (int ln = 0; ln < 8; ++ln) acc[ln] = MFMA16(whA[ln * 8 + kc], b, acc[ln]);
    }
    #pragma unroll
    for (int kc = 0; kc < 5; ++kc) {
      const half8 b = hbr[(8 + kc) * 64 + L];
      #pragma unroll
      for (int ln = 0; ln < 8; ++ln) acc[ln] = MFMA16(whV[ln * 5 + kc], b, acc[ln]);
    }
    #pragma unroll
    for (int kc = 0; kc < 3; ++kc) {
      const half8 b = hbr[(13 + kc) * 64 + L];
      #pragma unroll
      for (int ln = 0; ln < 8; ++ln)
        acc[ln] = MFMA16(wl[((w * 8 + ln) * 3 + kc) * 64 + L], b, acc[ln]);
    }

    // epilogue: relu -> b64 writes into next buffer.
    // thread covers j = w*128 + ln*16 + 4kq + i, col n:
    // slot S = (w*16 + ln*2 + (kq>>1))*16 + n, half-offset 4*(kq&1)
    #pragma unroll
    for (int ln = 0; ln < 8; ++ln) {
      half4 hv;
      #pragma unroll
      for (int i = 0; i < 4; ++i) hv[i] = (_Float16)fmaxf(acc[ln][i], 0.f);
      const int S = (w * 16 + ln * 2 + (kq >> 1)) * 16 + n;
      *(half4*)&hbw[S * 8 + 4 * (kq & 1)] = hv;
    }
    __syncthreads();   // writes to nxt done; reads of cur complete
  }

  // ---- output 1: h_last (1,B,H) fp32 at out+4096 (final h in buffer 0) ----
  const half8* hf = (const half8*)hb;   // buffer 0
  #pragma unroll
  for (int u = 0; u < 4; ++u) {
    const int k8 = (tid >> 4) * 4 + u, nb = tid & 15;
    const half8 v = hf[k8 * 16 + nb];
    float* dst = out + 4096 + (g * 16 + nb) * H_ + k8 * 8;
    #pragma unroll
    for (int e = 0; e < 8; ++e) dst[e] = (float)v[e];
  }
  // ---- output 0: FC (reuse wlds as fp32 [16][513]) ----
  __syncthreads();
  float* wfcf = (float*)wlds;
  #pragma unroll
  for (int u = 0; u < 32; ++u) {
    const int idx = tid + u * 256;
    wfcf[(idx >> 9) * 513 + (idx & 511)] = W_fc[idx];
  }
  __syncthreads();
  {
    const int bl = tid >> 4, o = tid & 15;
    float s = 0.f;
    #pragma unroll 8
    for (int k8 = 0; k8 < 64; ++k8) {
      const half8 v = hf[k8 * 16 + bl];
      #pragma unroll
      for (int e = 0; e < 8; ++e) s += (float)v[e] * wfcf[o * 513 + k8 * 8 + e];
    }
    out[(g * 16 + bl) * 16 + o] = s + b_fc[o];
  }
}

extern "C" void kernel_launch(void* const* d_in, const int* in_sizes, int n_in,
                              void* d_out, int out_size, void* d_ws, size_t ws_size,
                              hipStream_t stream) {
  const float* x    = (const float*)d_in[0];
  const float* h0   = (const float*)d_in[1];
  const float* W_ih = (const float*)d_in[2];
  const float* W_hh = (const float*)d_in[3];
  const float* b_ih = (const float*)d_in[4];
  const float* b_hh = (const float*)d_in[5];
  const float* W_fc = (const float*)d_in[6];
  const float* b_fc = (const float*)d_in[7];
  float* out = (float*)d_out;

  _Float16* xp = (_Float16*)d_ws;   // 134 MB f16 workspace

  xp_prepass<<<dim3(512), dim3(256), 0, stream>>>(x, W_ih, b_ih, b_hh, xp);
  rnn_persist<<<dim3(16), dim3(256), 0, stream>>>(h0, W_hh, W_fc, b_fc, out, xp);
}